// Round 1
// baseline (427.528 us; speedup 1.0000x reference)
//
#include <hip/hip_runtime.h>
#include <hip/hip_bf16.h>

#define N_NODES 50000
#define N_EDGES 800000

typedef __attribute__((ext_vector_type(8))) short short8;
typedef __attribute__((ext_vector_type(4))) float floatx4;

static __device__ __forceinline__ float bf16_bits_to_f32(unsigned int hi16) {
  union { unsigned int u; float f; } c; c.u = hi16 << 16; return c.f;
}
static __device__ __forceinline__ unsigned short f32_to_bf16_rne(float f) {
  union { float f; unsigned int u; } c; c.f = f;
  unsigned int u = c.u;
  unsigned int r = (u + 0x7fffu + ((u >> 16) & 1u)) >> 16;
  return (unsigned short)r;
}

__global__ void zero_kernel(int* __restrict__ p, int n) {
  int i = blockIdx.x * blockDim.x + threadIdx.x;
  if (i < n) p[i] = 0;
}

// fp32 -> packed bf16x2, n2 = element_count/2
__global__ void cvt_bf16x2_kernel(const float2* __restrict__ in,
                                  unsigned int* __restrict__ out, int n2) {
  int i = blockIdx.x * blockDim.x + threadIdx.x;
  if (i < n2) {
    float2 v = in[i];
    out[i] = (unsigned int)f32_to_bf16_rne(v.x) |
             ((unsigned int)f32_to_bf16_rne(v.y) << 16);
  }
}

// all four weight matrices in one launch (segments in float2 units)
__global__ void cvt_w_kernel(const float2* __restrict__ w1l, const float2* __restrict__ w1r,
                             const float2* __restrict__ w2l, const float2* __restrict__ w2r,
                             unsigned int* __restrict__ o1l, unsigned int* __restrict__ o1r,
                             unsigned int* __restrict__ o2l, unsigned int* __restrict__ o2r) {
  int i = blockIdx.x * blockDim.x + threadIdx.x;  // 0..24575
  const float2* in; unsigned int* out; int j;
  if (i < 8192)        { in = w1l; out = o1l; j = i; }
  else if (i < 16384)  { in = w1r; out = o1r; j = i - 8192; }
  else if (i < 20480)  { in = w2l; out = o2l; j = i - 16384; }
  else if (i < 24576)  { in = w2r; out = o2r; j = i - 20480; }
  else return;
  float2 v = in[j];
  out[j] = (unsigned int)f32_to_bf16_rne(v.x) |
           ((unsigned int)f32_to_bf16_rne(v.y) << 16);
}

__global__ void hist_kernel(const int* __restrict__ dst, int* __restrict__ cnt) {
  int e = blockIdx.x * blockDim.x + threadIdx.x;
  if (e < N_EDGES) atomicAdd(&cnt[dst[e]], 1);
}

// single-block exclusive scan over N_NODES counts -> offs[0..N_NODES]
__global__ void scan_kernel(const int* __restrict__ cnt, int* __restrict__ offs) {
  __shared__ int wsum[16];
  __shared__ int carry_s;
  const int lane = threadIdx.x & 63, wid = threadIdx.x >> 6;
  if (threadIdx.x == 0) carry_s = 0;
  __syncthreads();
  for (int base = 0; base < N_NODES; base += 1024) {
    int i = base + (int)threadIdx.x;
    int v = (i < N_NODES) ? cnt[i] : 0;
    int incl = v;
    #pragma unroll
    for (int d = 1; d < 64; d <<= 1) {
      int t = __shfl_up(incl, d, 64);
      if (lane >= d) incl += t;
    }
    if (lane == 63) wsum[wid] = incl;
    __syncthreads();
    if (threadIdx.x == 0) {
      int acc = carry_s;
      #pragma unroll
      for (int w = 0; w < 16; ++w) { int t = wsum[w]; wsum[w] = acc; acc += t; }
      carry_s = acc;
    }
    __syncthreads();
    if (i < N_NODES) offs[i] = wsum[wid] + (incl - v);
    __syncthreads();  // protect wsum before next iteration overwrites
  }
  if (threadIdx.x == 0) offs[N_NODES] = carry_s;
}

__global__ void fill_kernel(const int* __restrict__ src, const int* __restrict__ dst,
                            const int* __restrict__ offs, int* __restrict__ cursor,
                            int* __restrict__ eidx) {
  int e = blockIdx.x * blockDim.x + threadIdx.x;
  if (e < N_EDGES) {
    int d = dst[e];
    int pos = atomicAdd(&cursor[d], 1);
    eidx[offs[d] + pos] = src[e];
  }
}

// mean-aggregate: one wave per node, lane handles 2 channels (bf16x2), fp32 accum
__global__ void agg_kernel(const unsigned int* __restrict__ in,  // [n][64] bf16x2
                           const int* __restrict__ offs, const int* __restrict__ eidx,
                           unsigned int* __restrict__ out) {
  int lane = threadIdx.x & 63;
  int node = blockIdx.x * 4 + (threadIdx.x >> 6);
  if (node >= N_NODES) return;
  int e0 = offs[node], e1 = offs[node + 1];
  float ax = 0.f, ay = 0.f;
  for (int e = e0; e < e1; ++e) {
    int s = eidx[e];
    unsigned int v = in[(size_t)s * 64 + lane];
    ax += bf16_bits_to_f32(v & 0xffffu);
    ay += bf16_bits_to_f32(v >> 16);
  }
  float inv = 1.0f / fmaxf((float)(e1 - e0), 1.0f);
  ax *= inv; ay *= inv;
  out[(size_t)node * 64 + lane] =
      (unsigned int)f32_to_bf16_rne(ax) | ((unsigned int)f32_to_bf16_rne(ay) << 16);
}

// out[n][j] = (relu?)( sum_k Xa[n][k]*Wl[j][k] + sum_k Xb[n][k]*Wr[j][k] + bias[j] )
// 4 waves/block, wave handles 16 rows x COUT cols via 16x16x32 bf16 MFMA.
// A/B frag: elem[lane][t] = M[lane&15][kb + (lane>>4)*8 + t]  (m89-verified)
// C/D frag: row = (lane>>4)*4 + reg, col = lane&15             (m89-verified)
template<int COUT, bool RELU, bool OUT_BF16>
__global__ __launch_bounds__(256) void gemm_kernel(
    const unsigned short* __restrict__ Xa, const unsigned short* __restrict__ Xb,
    const unsigned short* __restrict__ Wl, const unsigned short* __restrict__ Wr,
    const float* __restrict__ bias, void* __restrict__ out) {
  constexpr int NT = COUT / 16;
  const int lane = threadIdx.x & 63, wave = threadIdx.x >> 6;
  const int quad = lane >> 4, r16 = lane & 15;
  const int row = blockIdx.x * 64 + wave * 16 + r16;
  const int arow = (row < N_NODES) ? row : (N_NODES - 1);

  floatx4 acc[NT];
  #pragma unroll
  for (int c = 0; c < NT; ++c) acc[c] = (floatx4){0.f, 0.f, 0.f, 0.f};

  const unsigned short* As[2] = {Xa, Xb};
  const unsigned short* Ws[2] = {Wl, Wr};
  #pragma unroll
  for (int s = 0; s < 2; ++s) {
    const unsigned short* Arow = As[s] + (size_t)arow * 128 + quad * 8;
    const unsigned short* Wbase = Ws[s] + quad * 8;
    #pragma unroll
    for (int kb = 0; kb < 128; kb += 32) {
      short8 a = *(const short8*)(Arow + kb);
      #pragma unroll
      for (int c = 0; c < NT; ++c) {
        int j = c * 16 + r16;
        short8 b = *(const short8*)(Wbase + (size_t)j * 128 + kb);
        acc[c] = __builtin_amdgcn_mfma_f32_16x16x32_bf16(a, b, acc[c], 0, 0, 0);
      }
    }
  }

  const int orow_base = blockIdx.x * 64 + wave * 16 + quad * 4;
  #pragma unroll
  for (int c = 0; c < NT; ++c) {
    int j = c * 16 + r16;
    float bv = bias[j];
    #pragma unroll
    for (int r = 0; r < 4; ++r) {
      int node = orow_base + r;
      if (node < N_NODES) {
        float v = acc[c][r] + bv;
        if (RELU) v = fmaxf(v, 0.f);
        if (OUT_BF16)
          ((unsigned short*)out)[(size_t)node * COUT + j] = f32_to_bf16_rne(v);
        else
          ((float*)out)[(size_t)node * COUT + j] = v;
      }
    }
  }
}

extern "C" void kernel_launch(void* const* d_in, const int* in_sizes, int n_in,
                              void* d_out, int out_size, void* d_ws, size_t ws_size,
                              hipStream_t stream) {
  (void)in_sizes; (void)n_in; (void)out_size; (void)ws_size;
  const float* x   = (const float*)d_in[0];
  const int*   ei  = (const int*)d_in[1];   // jnp.int64 downcast to int32 by default JAX x64-off
  const float* W1l = (const float*)d_in[2];
  const float* b1l = (const float*)d_in[3];
  const float* W1r = (const float*)d_in[4];
  const float* W2l = (const float*)d_in[5];
  const float* b2l = (const float*)d_in[6];
  const float* W2r = (const float*)d_in[7];
  const int* src = ei;
  const int* dst = ei + N_EDGES;

  char* ws = (char*)d_ws;
  size_t p = 0;
  auto alloc = [&](size_t bytes) {
    char* q = ws + p;
    p = (p + bytes + 255) & ~(size_t)255;
    return q;
  };
  int* cntcur = (int*)alloc((size_t)2 * N_NODES * 4);   // cnt | cursor
  int* cnt = cntcur;
  int* cursor = cntcur + N_NODES;
  int* offs = (int*)alloc((size_t)(N_NODES + 1) * 4);
  int* eidx = (int*)alloc((size_t)N_EDGES * 4);
  unsigned short* xb   = (unsigned short*)alloc((size_t)N_NODES * 128 * 2);
  unsigned short* hb   = (unsigned short*)alloc((size_t)N_NODES * 128 * 2);
  unsigned short* aggb = (unsigned short*)alloc((size_t)N_NODES * 128 * 2);
  unsigned short* w1lb = (unsigned short*)alloc(128 * 128 * 2);
  unsigned short* w1rb = (unsigned short*)alloc(128 * 128 * 2);
  unsigned short* w2lb = (unsigned short*)alloc(64 * 128 * 2);
  unsigned short* w2rb = (unsigned short*)alloc(64 * 128 * 2);

  // 1. zero cnt+cursor
  zero_kernel<<<(2 * N_NODES + 255) / 256, 256, 0, stream>>>(cntcur, 2 * N_NODES);
  // 2. convert x to bf16 (packed x2)
  const int xn2 = N_NODES * 128 / 2;  // 3,200,000
  cvt_bf16x2_kernel<<<(xn2 + 255) / 256, 256, 0, stream>>>(
      (const float2*)x, (unsigned int*)xb, xn2);
  // 3. convert weights to bf16
  cvt_w_kernel<<<(24576 + 255) / 256, 256, 0, stream>>>(
      (const float2*)W1l, (const float2*)W1r, (const float2*)W2l, (const float2*)W2r,
      (unsigned int*)w1lb, (unsigned int*)w1rb, (unsigned int*)w2lb, (unsigned int*)w2rb);
  // 4. CSR build: histogram -> scan -> scatter
  hist_kernel<<<(N_EDGES + 255) / 256, 256, 0, stream>>>(dst, cnt);
  scan_kernel<<<1, 1024, 0, stream>>>(cnt, offs);
  fill_kernel<<<(N_EDGES + 255) / 256, 256, 0, stream>>>(src, dst, offs, cursor, eidx);
  // 5. layer 1: agg(x) -> gemm(relu) -> h (bf16)
  agg_kernel<<<(N_NODES + 3) / 4, 256, 0, stream>>>(
      (const unsigned int*)xb, offs, eidx, (unsigned int*)aggb);
  gemm_kernel<128, true, true><<<(N_NODES + 63) / 64, 256, 0, stream>>>(
      aggb, xb, w1lb, w1rb, b1l, hb);
  // 6. layer 2: agg(h) -> gemm -> out (fp32)
  agg_kernel<<<(N_NODES + 3) / 4, 256, 0, stream>>>(
      (const unsigned int*)hb, offs, eidx, (unsigned int*)aggb);
  gemm_kernel<64, false, false><<<(N_NODES + 63) / 64, 256, 0, stream>>>(
      aggb, hb, w2lb, w2rb, b2l, d_out);
}

// Round 2
// 261.988 us; speedup vs baseline: 1.6319x; 1.6319x over previous
//
#include <hip/hip_runtime.h>
#include <hip/hip_bf16.h>

#define N_NODES 50000
#define N_EDGES 800000
#define N_TILES 196          // ceil(N_NODES/256)

typedef __attribute__((ext_vector_type(8))) short short8;
typedef __attribute__((ext_vector_type(4))) float floatx4;

static __device__ __forceinline__ float bf16_lo(unsigned int v) {
  union { unsigned int u; float f; } c; c.u = v << 16; return c.f;
}
static __device__ __forceinline__ float bf16_hi(unsigned int v) {
  union { unsigned int u; float f; } c; c.u = v & 0xffff0000u; return c.f;
}
static __device__ __forceinline__ unsigned short f32_to_bf16_rne(float f) {
  union { float f; unsigned int u; } c; c.f = f;
  unsigned int u = c.u;
  unsigned int r = (u + 0x7fffu + ((u >> 16) & 1u)) >> 16;
  return (unsigned short)r;
}
static __device__ __forceinline__ unsigned int pack2(float a, float b) {
  return (unsigned int)f32_to_bf16_rne(a) | ((unsigned int)f32_to_bf16_rne(b) << 16);
}

// ---------------------------------------------------------------------------
// One kernel: convert x (fp32->bf16x2), convert 4 weight mats, zero cnt+cursor
//   [0, XN2)                    : x
//   [XN2, XN2+24576)            : weights (w1l 8192 | w1r 8192 | w2l 4096 | w2r 4096)
//   [XN2+24576, XN2+24576+25000): zero 2*N_NODES ints via uint4
// ---------------------------------------------------------------------------
#define XN2 (N_NODES * 64)   // 3,200,000 float2 elements of x
__global__ void prep_kernel(const float2* __restrict__ x, unsigned int* __restrict__ xb,
                            const float2* __restrict__ w1l, const float2* __restrict__ w1r,
                            const float2* __restrict__ w2l, const float2* __restrict__ w2r,
                            unsigned int* __restrict__ o1l, unsigned int* __restrict__ o1r,
                            unsigned int* __restrict__ o2l, unsigned int* __restrict__ o2r,
                            uint4* __restrict__ zero_p) {
  int i = blockIdx.x * blockDim.x + threadIdx.x;
  if (i < XN2) {
    float2 v = x[i];
    xb[i] = pack2(v.x, v.y);
    return;
  }
  int j = i - XN2;
  if (j < 24576) {
    const float2* in; unsigned int* out; int k;
    if (j < 8192)        { in = w1l; out = o1l; k = j; }
    else if (j < 16384)  { in = w1r; out = o1r; k = j - 8192; }
    else if (j < 20480)  { in = w2l; out = o2l; k = j - 16384; }
    else                 { in = w2r; out = o2r; k = j - 20480; }
    float2 v = in[k];
    out[k] = pack2(v.x, v.y);
    return;
  }
  int z = j - 24576;
  if (z < 25000) zero_p[z] = (uint4){0u, 0u, 0u, 0u};
}

__global__ void hist_kernel(const int* __restrict__ dst, int* __restrict__ cnt) {
  int e = blockIdx.x * blockDim.x + threadIdx.x;
  if (e < N_EDGES) atomicAdd(&cnt[dst[e]], 1);
}

// ---- 3-phase exclusive scan of cnt[N_NODES] -> offs[N_NODES+1] ----
__global__ __launch_bounds__(256) void scan1_kernel(const int* __restrict__ cnt,
                                                    int* __restrict__ offs,
                                                    int* __restrict__ tsum) {
  const int lane = threadIdx.x & 63, wid = threadIdx.x >> 6;
  int i = blockIdx.x * 256 + threadIdx.x;
  int v = (i < N_NODES) ? cnt[i] : 0;
  int incl = v;
  #pragma unroll
  for (int d = 1; d < 64; d <<= 1) {
    int t = __shfl_up(incl, d, 64);
    if (lane >= d) incl += t;
  }
  __shared__ int ws[4];
  if (lane == 63) ws[wid] = incl;
  __syncthreads();
  int add = 0;
  #pragma unroll
  for (int w = 0; w < 4; ++w) if (w < wid) add += ws[w];
  if (i < N_NODES) offs[i] = add + (incl - v);   // tile-local exclusive
  if (threadIdx.x == 255) tsum[blockIdx.x] = add + incl;
}

__global__ __launch_bounds__(256) void scan2_kernel(const int* __restrict__ tsum,
                                                    int* __restrict__ toffs,
                                                    int* __restrict__ offs) {
  const int lane = threadIdx.x & 63, wid = threadIdx.x >> 6;
  int v = (threadIdx.x < N_TILES) ? tsum[threadIdx.x] : 0;
  int incl = v;
  #pragma unroll
  for (int d = 1; d < 64; d <<= 1) {
    int t = __shfl_up(incl, d, 64);
    if (lane >= d) incl += t;
  }
  __shared__ int ws[4];
  if (lane == 63) ws[wid] = incl;
  __syncthreads();
  int add = 0;
  #pragma unroll
  for (int w = 0; w < 4; ++w) if (w < wid) add += ws[w];
  if (threadIdx.x < N_TILES) toffs[threadIdx.x] = add + (incl - v);
  if (threadIdx.x == 0) offs[N_NODES] = N_EDGES;  // total is known
}

__global__ __launch_bounds__(256) void scan3_kernel(int* __restrict__ offs,
                                                    const int* __restrict__ toffs) {
  int i = blockIdx.x * 256 + threadIdx.x;
  if (i < N_NODES) offs[i] += toffs[blockIdx.x];
}

__global__ void fill_kernel(const int* __restrict__ src, const int* __restrict__ dst,
                            const int* __restrict__ offs, int* __restrict__ cursor,
                            int* __restrict__ eidx) {
  int e = blockIdx.x * blockDim.x + threadIdx.x;
  if (e < N_EDGES) {
    int d = dst[e];
    int pos = atomicAdd(&cursor[d], 1);
    eidx[offs[d] + pos] = src[e];
  }
}

// ---------------------------------------------------------------------------
// Mean-aggregate, one wave/node. Lanes split 4 (edge slot) x 16 (16B chunk):
// 4 full 256B rows in flight per pass, unrolled x2 -> 8 row loads in flight.
// fp32 accumulate (8 ch/lane), butterfly-reduce edge slots, bf16x8 store.
// ---------------------------------------------------------------------------
__global__ __launch_bounds__(256) void agg_kernel(
    const uint4* __restrict__ in,    // [n][16] uint4 (128 bf16/row)
    const int* __restrict__ offs, const int* __restrict__ eidx,
    uint4* __restrict__ out) {
  const int lane = threadIdx.x & 63;
  const int sub = lane >> 4;   // edge slot 0..3
  const int l16 = lane & 15;   // 16B chunk within row
  int node = blockIdx.x * 4 + (threadIdx.x >> 6);
  if (node >= N_NODES) return;
  int e0 = offs[node], e1 = offs[node + 1];

  float acc[8];
  #pragma unroll
  for (int t = 0; t < 8; ++t) acc[t] = 0.f;

  int e = e0;
  for (; e + 8 <= e1; e += 8) {
    int s0 = eidx[e + sub];
    int s1 = eidx[e + 4 + sub];
    uint4 v0 = in[(size_t)s0 * 16 + l16];
    uint4 v1 = in[(size_t)s1 * 16 + l16];
    acc[0] += bf16_lo(v0.x); acc[1] += bf16_hi(v0.x);
    acc[2] += bf16_lo(v0.y); acc[3] += bf16_hi(v0.y);
    acc[4] += bf16_lo(v0.z); acc[5] += bf16_hi(v0.z);
    acc[6] += bf16_lo(v0.w); acc[7] += bf16_hi(v0.w);
    acc[0] += bf16_lo(v1.x); acc[1] += bf16_hi(v1.x);
    acc[2] += bf16_lo(v1.y); acc[3] += bf16_hi(v1.y);
    acc[4] += bf16_lo(v1.z); acc[5] += bf16_hi(v1.z);
    acc[6] += bf16_lo(v1.w); acc[7] += bf16_hi(v1.w);
  }
  for (; e < e1; e += 4) {
    int ee = e + sub;
    if (ee < e1) {
      int s = eidx[ee];
      uint4 v = in[(size_t)s * 16 + l16];
      acc[0] += bf16_lo(v.x); acc[1] += bf16_hi(v.x);
      acc[2] += bf16_lo(v.y); acc[3] += bf16_hi(v.y);
      acc[4] += bf16_lo(v.z); acc[5] += bf16_hi(v.z);
      acc[6] += bf16_lo(v.w); acc[7] += bf16_hi(v.w);
    }
  }
  // reduce the 4 edge slots (lanes l16, l16+16, l16+32, l16+48)
  #pragma unroll
  for (int d = 16; d < 64; d <<= 1) {
    #pragma unroll
    for (int t = 0; t < 8; ++t) acc[t] += __shfl_xor(acc[t], d, 64);
  }
  if (sub == 0) {
    float inv = 1.0f / fmaxf((float)(e1 - e0), 1.0f);
    uint4 o;
    o.x = pack2(acc[0] * inv, acc[1] * inv);
    o.y = pack2(acc[2] * inv, acc[3] * inv);
    o.z = pack2(acc[4] * inv, acc[5] * inv);
    o.w = pack2(acc[6] * inv, acc[7] * inv);
    out[(size_t)node * 16 + l16] = o;
  }
}

// ---------------------------------------------------------------------------
// out[n][j] = (relu?)( Xa[n]·Wl[j] + Xb[n]·Wr[j] + bias[j] )
// Wave owns 64 output cols; all B fragments register-cached (32 x short8);
// grid-strides over TPW row tiles of 16.
// A/B frag: elem[lane][t] = M[lane&15][kb*32 + (lane>>4)*8 + t]   (m89)
// C/D frag: row = (lane>>4)*4 + reg, col = lane&15                (m89)
// ---------------------------------------------------------------------------
template<int COUT, bool RELU, bool OUT_BF16, int TPW>
__global__ __launch_bounds__(256) void gemm_kernel(
    const unsigned short* __restrict__ Xa, const unsigned short* __restrict__ Xb,
    const unsigned short* __restrict__ Wl, const unsigned short* __restrict__ Wr,
    const float* __restrict__ bias, void* __restrict__ out) {
  constexpr int CG = COUT / 64;      // col groups (2 for 128, 1 for 64)
  constexpr int TW = 4 / CG;         // row-tile waves per block
  const int lane = threadIdx.x & 63, wave = threadIdx.x >> 6;
  const int quad = lane >> 4, r16 = lane & 15;
  const int cg  = (CG == 2) ? (wave & 1) : 0;
  const int tw  = (CG == 2) ? (wave >> 1) : wave;
  const int col0 = cg * 64;

  // preload B fragments: 2 src x 4 kb x 4 coltiles
  short8 bf[2][4][4];
  float bv[4];
  #pragma unroll
  for (int s = 0; s < 2; ++s) {
    const unsigned short* W = s ? Wr : Wl;
    #pragma unroll
    for (int kb = 0; kb < 4; ++kb)
      #pragma unroll
      for (int c = 0; c < 4; ++c) {
        int j = col0 + c * 16 + r16;
        bf[s][kb][c] = *(const short8*)(W + (size_t)j * 128 + kb * 32 + quad * 8);
      }
  }
  #pragma unroll
  for (int c = 0; c < 4; ++c) bv[c] = bias[col0 + c * 16 + r16];

  int tile = (blockIdx.x * TW + tw) * TPW;
  for (int t = 0; t < TPW; ++t, ++tile) {
    if (tile * 16 >= N_NODES) return;
    int row = tile * 16 + r16;
    int arow = (row < N_NODES) ? row : (N_NODES - 1);

    floatx4 acc[4] = {};
    #pragma unroll
    for (int s = 0; s < 2; ++s) {
      const unsigned short* X = s ? Xb : Xa;
      const unsigned short* Ar = X + (size_t)arow * 128 + quad * 8;
      #pragma unroll
      for (int kb = 0; kb < 4; ++kb) {
        short8 a = *(const short8*)(Ar + kb * 32);
        #pragma unroll
        for (int c = 0; c < 4; ++c)
          acc[c] = __builtin_amdgcn_mfma_f32_16x16x32_bf16(a, bf[s][kb][c], acc[c], 0, 0, 0);
      }
    }

    int orow0 = tile * 16 + quad * 4;
    #pragma unroll
    for (int c = 0; c < 4; ++c) {
      int j = col0 + c * 16 + r16;
      #pragma unroll
      for (int r = 0; r < 4; ++r) {
        int node = orow0 + r;
        if (node < N_NODES) {
          float v = acc[c][r] + bv[c];
          if (RELU) v = fmaxf(v, 0.f);
          if (OUT_BF16)
            ((unsigned short*)out)[(size_t)node * COUT + j] = f32_to_bf16_rne(v);
          else
            ((float*)out)[(size_t)node * COUT + j] = v;
        }
      }
    }
  }
}

extern "C" void kernel_launch(void* const* d_in, const int* in_sizes, int n_in,
                              void* d_out, int out_size, void* d_ws, size_t ws_size,
                              hipStream_t stream) {
  (void)in_sizes; (void)n_in; (void)out_size; (void)ws_size;
  const float* x   = (const float*)d_in[0];
  const int*   ei  = (const int*)d_in[1];
  const float* W1l = (const float*)d_in[2];
  const float* b1l = (const float*)d_in[3];
  const float* W1r = (const float*)d_in[4];
  const float* W2l = (const float*)d_in[5];
  const float* b2l = (const float*)d_in[6];
  const float* W2r = (const float*)d_in[7];
  const int* src = ei;
  const int* dst = ei + N_EDGES;

  char* ws = (char*)d_ws;
  size_t p = 0;
  auto alloc = [&](size_t bytes) {
    char* q = ws + p;
    p = (p + bytes + 255) & ~(size_t)255;
    return q;
  };
  int* cntcur = (int*)alloc((size_t)2 * N_NODES * 4);   // cnt | cursor (zeroed in prep)
  int* cnt = cntcur;
  int* cursor = cntcur + N_NODES;
  int* offs  = (int*)alloc((size_t)(N_NODES + 1) * 4);
  int* eidx  = (int*)alloc((size_t)N_EDGES * 4);
  int* tsum  = (int*)alloc((size_t)N_TILES * 4);
  int* toffs = (int*)alloc((size_t)N_TILES * 4);
  unsigned short* xb   = (unsigned short*)alloc((size_t)N_NODES * 128 * 2);
  unsigned short* hb   = (unsigned short*)alloc((size_t)N_NODES * 128 * 2);
  unsigned short* aggb = (unsigned short*)alloc((size_t)N_NODES * 128 * 2);
  unsigned short* w1lb = (unsigned short*)alloc(128 * 128 * 2);
  unsigned short* w1rb = (unsigned short*)alloc(128 * 128 * 2);
  unsigned short* w2lb = (unsigned short*)alloc(64 * 128 * 2);
  unsigned short* w2rb = (unsigned short*)alloc(64 * 128 * 2);

  // 1. prep: convert x + weights to bf16, zero cnt/cursor
  const int prep_n = XN2 + 24576 + 25000;
  prep_kernel<<<(prep_n + 255) / 256, 256, 0, stream>>>(
      (const float2*)x, (unsigned int*)xb,
      (const float2*)W1l, (const float2*)W1r, (const float2*)W2l, (const float2*)W2r,
      (unsigned int*)w1lb, (unsigned int*)w1rb, (unsigned int*)w2lb, (unsigned int*)w2rb,
      (uint4*)cntcur);
  // 2. CSR build
  hist_kernel<<<(N_EDGES + 255) / 256, 256, 0, stream>>>(dst, cnt);
  scan1_kernel<<<N_TILES, 256, 0, stream>>>(cnt, offs, tsum);
  scan2_kernel<<<1, 256, 0, stream>>>(tsum, toffs, offs);
  scan3_kernel<<<N_TILES, 256, 0, stream>>>(offs, toffs);
  fill_kernel<<<(N_EDGES + 255) / 256, 256, 0, stream>>>(src, dst, offs, cursor, eidx);
  // 3. layer 1: agg(x) -> gemm(relu) -> h (bf16)
  agg_kernel<<<(N_NODES + 3) / 4, 256, 0, stream>>>(
      (const uint4*)xb, offs, eidx, (uint4*)aggb);
  gemm_kernel<128, true, true, 4><<<391, 256, 0, stream>>>(
      aggb, xb, w1lb, w1rb, b1l, hb);
  // 4. layer 2: agg(h) -> gemm -> out (fp32)
  agg_kernel<<<(N_NODES + 3) / 4, 256, 0, stream>>>(
      (const uint4*)hb, offs, eidx, (uint4*)aggb);
  gemm_kernel<64, false, false, 4><<<196, 256, 0, stream>>>(
      aggb, hb, w2lb, w2rb, b2l, d_out);
}

// Round 3
// 216.174 us; speedup vs baseline: 1.9777x; 1.2119x over previous
//
#include <hip/hip_runtime.h>
#include <hip/hip_bf16.h>

#define N_NODES 50000
#define N_EDGES 800000
#define N_BUCKETS 196        // ceil(N_NODES/256), bucket = dst >> 8
#define BUCKET_CAP 8192      // mean 4096/bucket, +64 sigma slop
#define EPB 1024             // edges per block in bucket_kernel

typedef __attribute__((ext_vector_type(8))) short short8;
typedef __attribute__((ext_vector_type(4))) float floatx4;

static __device__ __forceinline__ float bf16_lo(unsigned int v) {
  union { unsigned int u; float f; } c; c.u = v << 16; return c.f;
}
static __device__ __forceinline__ float bf16_hi(unsigned int v) {
  union { unsigned int u; float f; } c; c.u = v & 0xffff0000u; return c.f;
}
static __device__ __forceinline__ unsigned short f32_to_bf16_rne(float f) {
  union { float f; unsigned int u; } c; c.f = f;
  unsigned int u = c.u;
  unsigned int r = (u + 0x7fffu + ((u >> 16) & 1u)) >> 16;
  return (unsigned short)r;
}
static __device__ __forceinline__ unsigned int pack2(float a, float b) {
  return (unsigned int)f32_to_bf16_rne(a) | ((unsigned int)f32_to_bf16_rne(b) << 16);
}

// ---------------------------------------------------------------------------
// prep: convert x (fp32->bf16x2), convert 4 weight mats, zero bucket cursors
// ---------------------------------------------------------------------------
#define XN2 (N_NODES * 64)   // 3,200,000 float2 elements of x
__global__ void prep_kernel(const float2* __restrict__ x, unsigned int* __restrict__ xb,
                            const float2* __restrict__ w1l, const float2* __restrict__ w1r,
                            const float2* __restrict__ w2l, const float2* __restrict__ w2r,
                            unsigned int* __restrict__ o1l, unsigned int* __restrict__ o1r,
                            unsigned int* __restrict__ o2l, unsigned int* __restrict__ o2r,
                            int* __restrict__ bcur) {
  int i = blockIdx.x * blockDim.x + threadIdx.x;
  if (i < XN2) {
    float2 v = x[i];
    xb[i] = pack2(v.x, v.y);
    return;
  }
  int j = i - XN2;
  if (j < 24576) {
    const float2* in; unsigned int* out; int k;
    if (j < 8192)        { in = w1l; out = o1l; k = j; }
    else if (j < 16384)  { in = w1r; out = o1r; k = j - 8192; }
    else if (j < 20480)  { in = w2l; out = o2l; k = j - 16384; }
    else                 { in = w2r; out = o2r; k = j - 20480; }
    float2 v = in[k];
    out[k] = pack2(v.x, v.y);
    return;
  }
  int z = j - 24576;
  if (z < N_BUCKETS) bcur[z] = 0;
}

// ---------------------------------------------------------------------------
// Pass A: bucket edges by dst>>8. LDS histogram gives local rank; one global
// atomic-return per (block,bucket); scatter packed (dst&255)<<16|src u32.
// ---------------------------------------------------------------------------
__global__ __launch_bounds__(256) void bucket_kernel(
    const int* __restrict__ src, const int* __restrict__ dst,
    int* __restrict__ bcur, unsigned int* __restrict__ ebuf) {
  __shared__ int hist[N_BUCKETS];
  __shared__ int base[N_BUCKETS];
  for (int i = threadIdx.x; i < N_BUCKETS; i += 256) hist[i] = 0;
  __syncthreads();
  const int e0 = blockIdx.x * EPB;
  int bk[4], rk[4];
  unsigned int pk[4];
  bool val[4];
  #pragma unroll
  for (int k = 0; k < 4; ++k) {
    int e = e0 + k * 256 + threadIdx.x;
    val[k] = (e < N_EDGES);
    if (val[k]) {
      int d = dst[e], s = src[e];
      bk[k] = d >> 8;
      pk[k] = ((unsigned int)(d & 255) << 16) | (unsigned int)s;
      rk[k] = atomicAdd(&hist[bk[k]], 1);
    }
  }
  __syncthreads();
  for (int i = threadIdx.x; i < N_BUCKETS; i += 256)
    base[i] = hist[i] ? atomicAdd(&bcur[i], hist[i]) : 0;
  __syncthreads();
  #pragma unroll
  for (int k = 0; k < 4; ++k) {
    if (val[k]) {
      int p = base[bk[k]] + rk[k];
      if (p < BUCKET_CAP) ebuf[(size_t)bk[k] * BUCKET_CAP + p] = pk[k];
    }
  }
}

// ---------------------------------------------------------------------------
// Pass B: one block per bucket. LDS 256-bin histogram + in-block scan ->
// per-node start/count (coalesced global write), then scatter src ids into
// the bucket-local eidx region (32 KB, cache-resident).
// ---------------------------------------------------------------------------
__global__ __launch_bounds__(256) void local_csr_kernel(
    const unsigned int* __restrict__ ebuf, const int* __restrict__ bcur,
    int* __restrict__ start_g, int* __restrict__ cnt_g, int* __restrict__ eidx) {
  const int b = blockIdx.x;
  const int nb = min(bcur[b], BUCKET_CAP);
  __shared__ int cnt[256];
  __shared__ int loff[256];
  __shared__ int ws[4];
  cnt[threadIdx.x] = 0;
  __syncthreads();
  const unsigned int* eb = ebuf + (size_t)b * BUCKET_CAP;
  for (int i = threadIdx.x; i < nb; i += 256)
    atomicAdd(&cnt[eb[i] >> 16], 1);
  __syncthreads();
  // exclusive scan of cnt[256]
  const int lane = threadIdx.x & 63, wid = threadIdx.x >> 6;
  int v = cnt[threadIdx.x];
  int incl = v;
  #pragma unroll
  for (int d = 1; d < 64; d <<= 1) {
    int t = __shfl_up(incl, d, 64);
    if (lane >= d) incl += t;
  }
  if (lane == 63) ws[wid] = incl;
  __syncthreads();
  int add = 0;
  #pragma unroll
  for (int w = 0; w < 4; ++w) if (w < wid) add += ws[w];
  int excl = add + incl - v;
  loff[threadIdx.x] = excl;
  int node = b * 256 + threadIdx.x;
  if (node < N_NODES) {
    start_g[node] = b * BUCKET_CAP + excl;
    cnt_g[node] = v;
  }
  __syncthreads();
  for (int i = threadIdx.x; i < nb; i += 256) {
    unsigned int p = eb[i];
    int local = p >> 16;
    int pos = atomicAdd(&loff[local], 1);
    eidx[(size_t)b * BUCKET_CAP + pos] = (int)(p & 0xffffu);
  }
}

// ---------------------------------------------------------------------------
// Mean-aggregate, one wave/node. Lanes split 4 (edge slot) x 16 (16B chunk):
// up to 8 row loads in flight per wave; fp32 accum; butterfly-reduce slots.
// ---------------------------------------------------------------------------
__global__ __launch_bounds__(256) void agg_kernel(
    const uint4* __restrict__ in,    // [n][16] uint4 (128 bf16/row)
    const int* __restrict__ start_g, const int* __restrict__ cnt_g,
    const int* __restrict__ eidx, uint4* __restrict__ out) {
  const int lane = threadIdx.x & 63;
  const int sub = lane >> 4;   // edge slot 0..3
  const int l16 = lane & 15;   // 16B chunk within row
  int node = blockIdx.x * 4 + (threadIdx.x >> 6);
  if (node >= N_NODES) return;
  int e0 = start_g[node];
  int c = cnt_g[node];
  int e1 = e0 + c;

  float acc[8];
  #pragma unroll
  for (int t = 0; t < 8; ++t) acc[t] = 0.f;

  int e = e0;
  for (; e + 8 <= e1; e += 8) {
    int s0 = eidx[e + sub];
    int s1 = eidx[e + 4 + sub];
    uint4 v0 = in[(size_t)s0 * 16 + l16];
    uint4 v1 = in[(size_t)s1 * 16 + l16];
    acc[0] += bf16_lo(v0.x); acc[1] += bf16_hi(v0.x);
    acc[2] += bf16_lo(v0.y); acc[3] += bf16_hi(v0.y);
    acc[4] += bf16_lo(v0.z); acc[5] += bf16_hi(v0.z);
    acc[6] += bf16_lo(v0.w); acc[7] += bf16_hi(v0.w);
    acc[0] += bf16_lo(v1.x); acc[1] += bf16_hi(v1.x);
    acc[2] += bf16_lo(v1.y); acc[3] += bf16_hi(v1.y);
    acc[4] += bf16_lo(v1.z); acc[5] += bf16_hi(v1.z);
    acc[6] += bf16_lo(v1.w); acc[7] += bf16_hi(v1.w);
  }
  for (; e < e1; e += 4) {
    int ee = e + sub;
    if (ee < e1) {
      int s = eidx[ee];
      uint4 v = in[(size_t)s * 16 + l16];
      acc[0] += bf16_lo(v.x); acc[1] += bf16_hi(v.x);
      acc[2] += bf16_lo(v.y); acc[3] += bf16_hi(v.y);
      acc[4] += bf16_lo(v.z); acc[5] += bf16_hi(v.z);
      acc[6] += bf16_lo(v.w); acc[7] += bf16_hi(v.w);
    }
  }
  #pragma unroll
  for (int d = 16; d < 64; d <<= 1) {
    #pragma unroll
    for (int t = 0; t < 8; ++t) acc[t] += __shfl_xor(acc[t], d, 64);
  }
  if (sub == 0) {
    float inv = 1.0f / fmaxf((float)c, 1.0f);
    uint4 o;
    o.x = pack2(acc[0] * inv, acc[1] * inv);
    o.y = pack2(acc[2] * inv, acc[3] * inv);
    o.z = pack2(acc[4] * inv, acc[5] * inv);
    o.w = pack2(acc[6] * inv, acc[7] * inv);
    out[(size_t)node * 16 + l16] = o;
  }
}

// ---------------------------------------------------------------------------
// out[n][j] = (relu?)( Xa[n]·Wl[j] + Xb[n]·Wr[j] + bias[j] )
// Wave owns 64 output cols; B fragments register-cached; TPW row tiles.
// ---------------------------------------------------------------------------
template<int COUT, bool RELU, bool OUT_BF16, int TPW>
__global__ __launch_bounds__(256) void gemm_kernel(
    const unsigned short* __restrict__ Xa, const unsigned short* __restrict__ Xb,
    const unsigned short* __restrict__ Wl, const unsigned short* __restrict__ Wr,
    const float* __restrict__ bias, void* __restrict__ out) {
  constexpr int CG = COUT / 64;
  constexpr int TW = 4 / CG;
  const int lane = threadIdx.x & 63, wave = threadIdx.x >> 6;
  const int quad = lane >> 4, r16 = lane & 15;
  const int cg  = (CG == 2) ? (wave & 1) : 0;
  const int tw  = (CG == 2) ? (wave >> 1) : wave;
  const int col0 = cg * 64;

  short8 bf[2][4][4];
  float bv[4];
  #pragma unroll
  for (int s = 0; s < 2; ++s) {
    const unsigned short* W = s ? Wr : Wl;
    #pragma unroll
    for (int kb = 0; kb < 4; ++kb)
      #pragma unroll
      for (int c = 0; c < 4; ++c) {
        int j = col0 + c * 16 + r16;
        bf[s][kb][c] = *(const short8*)(W + (size_t)j * 128 + kb * 32 + quad * 8);
      }
  }
  #pragma unroll
  for (int c = 0; c < 4; ++c) bv[c] = bias[col0 + c * 16 + r16];

  int tile = (blockIdx.x * TW + tw) * TPW;
  for (int t = 0; t < TPW; ++t, ++tile) {
    if (tile * 16 >= N_NODES) return;
    int row = tile * 16 + r16;
    int arow = (row < N_NODES) ? row : (N_NODES - 1);

    floatx4 acc[4] = {};
    #pragma unroll
    for (int s = 0; s < 2; ++s) {
      const unsigned short* X = s ? Xb : Xa;
      const unsigned short* Ar = X + (size_t)arow * 128 + quad * 8;
      #pragma unroll
      for (int kb = 0; kb < 4; ++kb) {
        short8 a = *(const short8*)(Ar + kb * 32);
        #pragma unroll
        for (int c = 0; c < 4; ++c)
          acc[c] = __builtin_amdgcn_mfma_f32_16x16x32_bf16(a, bf[s][kb][c], acc[c], 0, 0, 0);
      }
    }

    int orow0 = tile * 16 + quad * 4;
    #pragma unroll
    for (int c = 0; c < 4; ++c) {
      int j = col0 + c * 16 + r16;
      #pragma unroll
      for (int r = 0; r < 4; ++r) {
        int node = orow0 + r;
        if (node < N_NODES) {
          float v = acc[c][r] + bv[c];
          if (RELU) v = fmaxf(v, 0.f);
          if (OUT_BF16)
            ((unsigned short*)out)[(size_t)node * COUT + j] = f32_to_bf16_rne(v);
          else
            ((float*)out)[(size_t)node * COUT + j] = v;
        }
      }
    }
  }
}

extern "C" void kernel_launch(void* const* d_in, const int* in_sizes, int n_in,
                              void* d_out, int out_size, void* d_ws, size_t ws_size,
                              hipStream_t stream) {
  (void)in_sizes; (void)n_in; (void)out_size; (void)ws_size;
  const float* x   = (const float*)d_in[0];
  const int*   ei  = (const int*)d_in[1];
  const float* W1l = (const float*)d_in[2];
  const float* b1l = (const float*)d_in[3];
  const float* W1r = (const float*)d_in[4];
  const float* W2l = (const float*)d_in[5];
  const float* b2l = (const float*)d_in[6];
  const float* W2r = (const float*)d_in[7];
  const int* src = ei;
  const int* dst = ei + N_EDGES;

  char* ws = (char*)d_ws;
  size_t p = 0;
  auto alloc = [&](size_t bytes) {
    char* q = ws + p;
    p = (p + bytes + 255) & ~(size_t)255;
    return q;
  };
  int* bcur    = (int*)alloc((size_t)N_BUCKETS * 4);
  int* start_g = (int*)alloc((size_t)N_NODES * 4);
  int* cnt_g   = (int*)alloc((size_t)N_NODES * 4);
  unsigned int* ebuf = (unsigned int*)alloc((size_t)N_BUCKETS * BUCKET_CAP * 4);
  int* eidx    = (int*)alloc((size_t)N_BUCKETS * BUCKET_CAP * 4);
  unsigned short* xb   = (unsigned short*)alloc((size_t)N_NODES * 128 * 2);
  unsigned short* hb   = (unsigned short*)alloc((size_t)N_NODES * 128 * 2);
  unsigned short* aggb = (unsigned short*)alloc((size_t)N_NODES * 128 * 2);
  unsigned short* w1lb = (unsigned short*)alloc(128 * 128 * 2);
  unsigned short* w1rb = (unsigned short*)alloc(128 * 128 * 2);
  unsigned short* w2lb = (unsigned short*)alloc(64 * 128 * 2);
  unsigned short* w2rb = (unsigned short*)alloc(64 * 128 * 2);

  // 1. prep: bf16 conversions + zero bucket cursors
  const int prep_n = XN2 + 24576 + N_BUCKETS;
  prep_kernel<<<(prep_n + 255) / 256, 256, 0, stream>>>(
      (const float2*)x, (unsigned int*)xb,
      (const float2*)W1l, (const float2*)W1r, (const float2*)W2l, (const float2*)W2r,
      (unsigned int*)w1lb, (unsigned int*)w1rb, (unsigned int*)w2lb, (unsigned int*)w2rb,
      bcur);
  // 2. CSR build: bucket scatter -> per-bucket local CSR
  bucket_kernel<<<(N_EDGES + EPB - 1) / EPB, 256, 0, stream>>>(src, dst, bcur, ebuf);
  local_csr_kernel<<<N_BUCKETS, 256, 0, stream>>>(ebuf, bcur, start_g, cnt_g, eidx);
  // 3. layer 1: agg(x) -> gemm(relu) -> h (bf16)
  agg_kernel<<<(N_NODES + 3) / 4, 256, 0, stream>>>(
      (const uint4*)xb, start_g, cnt_g, eidx, (uint4*)aggb);
  gemm_kernel<128, true, true, 4><<<391, 256, 0, stream>>>(
      aggb, xb, w1lb, w1rb, b1l, hb);
  // 4. layer 2: agg(h) -> gemm -> out (fp32)
  agg_kernel<<<(N_NODES + 3) / 4, 256, 0, stream>>>(
      (const uint4*)hb, start_g, cnt_g, eidx, (uint4*)aggb);
  gemm_kernel<64, false, false, 4><<<196, 256, 0, stream>>>(
      aggb, hb, w2lb, w2rb, b2l, d_out);
}